// Round 1
// baseline (1502.023 us; speedup 1.0000x reference)
//
#include <hip/hip_runtime.h>
#include <math.h>

#define SEQ   168
#define BATCH 4096
#define INDIM 24
#define HID   64
#define NOUT  9
#define BC    16            // batch rows per block
#define NBLK  (BATCH/BC)    // 256 blocks -> 1 per CU

__device__ __forceinline__ float sigf(float x){
    x = fminf(fmaxf(x, -30.f), 30.f);
    return __builtin_amdgcn_rcpf(1.0f + __expf(-x));
}
__device__ __forceinline__ float tanhf_(float x){
    x = fminf(fmaxf(x, -15.f), 15.f);
    float e = __expf(2.0f * x);
    return (e - 1.0f) * __builtin_amdgcn_rcpf(e + 1.0f);
}

// ---------------- Layer 0: x[S,B,24] -> h0buf[chunk,B,64] ----------------
__global__ __launch_bounds__(256)
void lstm_l0(const float* __restrict__ x,
             const float* __restrict__ Wih, const float* __restrict__ Whh,
             const float* __restrict__ bih, const float* __restrict__ bhh,
             float* __restrict__ hstate, float* __restrict__ cstate,
             float* __restrict__ h0buf, int s0, int scnt)
{
    __shared__ float sWT[INDIM + HID][256]; // [k][4*u+gate], gate-interleaved W^T
    __shared__ float sIN[INDIM + HID][18];  // [k][row]; k<24: x_t, k>=24: h_{t-1}

    const int tid = threadIdx.x;
    const int u   = tid & 63;   // hidden unit
    const int rt  = tid >> 6;   // row group 0..3 (rows rt*4..rt*4+3)
    const int r0  = blockIdx.x * BC;

    // stage weights (gate-interleaved transpose): sWT[k][4u+g] = W[g*64+u][k]
    for (int idx = tid; idx < 256 * INDIM; idx += 256){
        int row = idx / INDIM, col = idx - row * INDIM;
        sWT[col][4 * (row & 63) + (row >> 6)] = Wih[idx];
    }
    for (int idx = tid; idx < 256 * HID; idx += 256){
        int row = idx >> 6, col = idx & 63;
        sWT[INDIM + col][4 * (row & 63) + (row >> 6)] = Whh[idx];
    }

    float c[4], hl[4];
    #pragma unroll
    for (int r = 0; r < 4; ++r){
        const int row = rt * 4 + r;
        if (s0 == 0){
            c[r] = 0.f;
            sIN[INDIM + u][row] = 0.f;
        } else {
            c[r] = cstate[(size_t)(r0 + row) * HID + u];
            sIN[INDIM + u][row] = hstate[(size_t)(r0 + row) * HID + u];
        }
    }
    const float bi = bih[u]       + bhh[u];
    const float bf = bih[64 + u]  + bhh[64 + u];
    const float bg = bih[128 + u] + bhh[128 + u];
    const float bo = bih[192 + u] + bhh[192 + u];
    __syncthreads();

    for (int si = 0; si < scnt; ++si){
        const int s = s0 + si;
        // stage x[s] for this block's rows (contiguous 16*24 floats, coalesced)
        for (int idx = tid; idx < BC * INDIM; idx += 256){
            sIN[idx % INDIM][idx / INDIM] =
                x[(size_t)(s * BATCH + r0) * INDIM + idx];
        }
        __syncthreads();

        float acc[4][4];
        #pragma unroll
        for (int r = 0; r < 4; ++r){ acc[0][r] = bi; acc[1][r] = bf; acc[2][r] = bg; acc[3][r] = bo; }

        #pragma unroll 8
        for (int k = 0; k < INDIM + HID; ++k){
            const float4 w  = *reinterpret_cast<const float4*>(&sWT[k][4 * u]);
            const float2 v0 = *reinterpret_cast<const float2*>(&sIN[k][4 * rt]);
            const float2 v1 = *reinterpret_cast<const float2*>(&sIN[k][4 * rt + 2]);
            const float hv[4] = {v0.x, v0.y, v1.x, v1.y};
            #pragma unroll
            for (int r = 0; r < 4; ++r){
                acc[0][r] = fmaf(w.x, hv[r], acc[0][r]);
                acc[1][r] = fmaf(w.y, hv[r], acc[1][r]);
                acc[2][r] = fmaf(w.z, hv[r], acc[2][r]);
                acc[3][r] = fmaf(w.w, hv[r], acc[3][r]);
            }
        }
        __syncthreads();

        #pragma unroll
        for (int r = 0; r < 4; ++r){
            const int row = rt * 4 + r;
            const float ig = sigf(acc[0][r]);
            const float fg = sigf(acc[1][r]);
            const float gg = tanhf_(acc[2][r]);
            const float og = sigf(acc[3][r]);
            c[r] = fg * c[r] + ig * gg;
            const float h = og * tanhf_(c[r]);
            hl[r] = h;
            sIN[INDIM + u][row] = h;
            h0buf[((size_t)si * BATCH + r0 + row) * HID + u] = h; // lanes u -> coalesced
        }
        __syncthreads();
    }
    #pragma unroll
    for (int r = 0; r < 4; ++r){
        const int row = rt * 4 + r;
        cstate[(size_t)(r0 + row) * HID + u] = c[r];
        hstate[(size_t)(r0 + row) * HID + u] = hl[r];
    }
}

// ------------- Layer 1 + head: h0buf -> out[S,B,9] -------------
__global__ __launch_bounds__(256)
void lstm_l1(const float* __restrict__ h0buf,
             const float* __restrict__ Wih, const float* __restrict__ Whh,
             const float* __restrict__ bih, const float* __restrict__ bhh,
             const float* __restrict__ Wout, const float* __restrict__ bout,
             float* __restrict__ hstate, float* __restrict__ cstate,
             float* __restrict__ out, int s0, int scnt)
{
    __shared__ float sWT[2 * HID][256];
    __shared__ float sIN[2 * HID][18];  // k<64: h0_t, k>=64: h1_{t-1}
    __shared__ float sH1[BC][68];       // row-major h1 copy for head
    __shared__ float sWo[NOUT][64];
    __shared__ float sbo[NOUT];

    const int tid = threadIdx.x;
    const int u   = tid & 63;
    const int rt  = tid >> 6;
    const int r0  = blockIdx.x * BC;

    for (int idx = tid; idx < 256 * HID; idx += 256){
        int row = idx >> 6, col = idx & 63;
        sWT[col][4 * (row & 63) + (row >> 6)] = Wih[idx];
    }
    for (int idx = tid; idx < 256 * HID; idx += 256){
        int row = idx >> 6, col = idx & 63;
        sWT[HID + col][4 * (row & 63) + (row >> 6)] = Whh[idx];
    }
    for (int idx = tid; idx < NOUT * 64; idx += 256)
        sWo[idx >> 6][idx & 63] = Wout[idx];
    if (tid < NOUT) sbo[tid] = bout[tid];

    float c[4], hl[4];
    #pragma unroll
    for (int r = 0; r < 4; ++r){
        const int row = rt * 4 + r;
        if (s0 == 0){
            c[r] = 0.f;
            sIN[HID + u][row] = 0.f;
        } else {
            c[r] = cstate[(size_t)(r0 + row) * HID + u];
            sIN[HID + u][row] = hstate[(size_t)(r0 + row) * HID + u];
        }
    }
    const float bi = bih[u]       + bhh[u];
    const float bf = bih[64 + u]  + bhh[64 + u];
    const float bg = bih[128 + u] + bhh[128 + u];
    const float bo = bih[192 + u] + bhh[192 + u];
    __syncthreads();

    for (int si = 0; si < scnt; ++si){
        const int s = s0 + si;
        // stage h0[s]: 1024 floats, one float4 per thread (coalesced)
        {
            const float4 v = *reinterpret_cast<const float4*>(
                &h0buf[((size_t)si * BATCH + r0) * HID + tid * 4]);
            const int r = tid >> 4;
            const int k = (tid & 15) * 4;
            sIN[k][r] = v.x; sIN[k + 1][r] = v.y; sIN[k + 2][r] = v.z; sIN[k + 3][r] = v.w;
        }
        __syncthreads();

        float acc[4][4];
        #pragma unroll
        for (int r = 0; r < 4; ++r){ acc[0][r] = bi; acc[1][r] = bf; acc[2][r] = bg; acc[3][r] = bo; }

        #pragma unroll 8
        for (int k = 0; k < 2 * HID; ++k){
            const float4 w  = *reinterpret_cast<const float4*>(&sWT[k][4 * u]);
            const float2 v0 = *reinterpret_cast<const float2*>(&sIN[k][4 * rt]);
            const float2 v1 = *reinterpret_cast<const float2*>(&sIN[k][4 * rt + 2]);
            const float hv[4] = {v0.x, v0.y, v1.x, v1.y};
            #pragma unroll
            for (int r = 0; r < 4; ++r){
                acc[0][r] = fmaf(w.x, hv[r], acc[0][r]);
                acc[1][r] = fmaf(w.y, hv[r], acc[1][r]);
                acc[2][r] = fmaf(w.z, hv[r], acc[2][r]);
                acc[3][r] = fmaf(w.w, hv[r], acc[3][r]);
            }
        }
        __syncthreads();

        #pragma unroll
        for (int r = 0; r < 4; ++r){
            const int row = rt * 4 + r;
            const float ig = sigf(acc[0][r]);
            const float fg = sigf(acc[1][r]);
            const float gg = tanhf_(acc[2][r]);
            const float og = sigf(acc[3][r]);
            c[r] = fg * c[r] + ig * gg;
            const float h = og * tanhf_(c[r]);
            hl[r] = h;
            sIN[HID + u][row] = h;
            sH1[row][u] = h;
        }
        __syncthreads();

        // head: out[s, r, o] = b_o + h1[r] . Wout[o]
        if (tid < BC * NOUT){
            const int r = tid & 15;
            const int o = tid >> 4;
            float a = sbo[o];
            #pragma unroll
            for (int k = 0; k < 64; k += 4){
                const float4 hv = *reinterpret_cast<const float4*>(&sH1[r][k]);
                const float4 wv = *reinterpret_cast<const float4*>(&sWo[o][k]);
                a += hv.x * wv.x + hv.y * wv.y + hv.z * wv.z + hv.w * wv.w;
            }
            out[((size_t)s * BATCH + r0 + r) * NOUT + o] = a;
        }
        // no trailing sync needed: next stage writes sIN[0..63] (disjoint from
        // sH1/sWo reads); next gate reads are behind the next barrier.
    }
    #pragma unroll
    for (int r = 0; r < 4; ++r){
        const int row = rt * 4 + r;
        cstate[(size_t)(r0 + row) * HID + u] = c[r];
        hstate[(size_t)(r0 + row) * HID + u] = hl[r];
    }
}

extern "C" void kernel_launch(void* const* d_in, const int* in_sizes, int n_in,
                              void* d_out, int out_size, void* d_ws, size_t ws_size,
                              hipStream_t stream)
{
    const float* x    = (const float*)d_in[0];
    const float* Wih0 = (const float*)d_in[1];
    const float* Whh0 = (const float*)d_in[2];
    const float* bih0 = (const float*)d_in[3];
    const float* bhh0 = (const float*)d_in[4];
    const float* Wih1 = (const float*)d_in[5];
    const float* Whh1 = (const float*)d_in[6];
    const float* bih1 = (const float*)d_in[7];
    const float* bhh1 = (const float*)d_in[8];
    const float* Wout = (const float*)d_in[9];
    const float* bout = (const float*)d_in[10];
    float* out = (float*)d_out;

    float* ws = (float*)d_ws;
    const size_t BH = (size_t)BATCH * HID;   // 262144 floats
    float* h0s   = ws;                        // layer-0 h carry
    float* c0s   = ws + BH;                   // layer-0 c carry
    float* h1s   = ws + 2 * BH;               // layer-1 h carry
    float* c1s   = ws + 3 * BH;               // layer-1 c carry
    float* h0buf = ws + 4 * BH;               // staging for h0 chunk

    const size_t avail_f = (ws_size / 4 > 4 * BH) ? (ws_size / 4 - 4 * BH) : 0;
    int chunk = (int)(avail_f / BH);
    if (chunk > SEQ) chunk = SEQ;
    if (chunk < 1)  chunk = 1;   // assumes ws_size >= ~5 MB

    for (int s0 = 0; s0 < SEQ; s0 += chunk){
        const int n = (SEQ - s0 < chunk) ? (SEQ - s0) : chunk;
        lstm_l0<<<NBLK, 256, 0, stream>>>(x, Wih0, Whh0, bih0, bhh0,
                                          h0s, c0s, h0buf, s0, n);
        lstm_l1<<<NBLK, 256, 0, stream>>>(h0buf, Wih1, Whh1, bih1, bhh1,
                                          Wout, bout, h1s, c1s, out, s0, n);
    }
}

// Round 2
// 375.901 us; speedup vs baseline: 3.9958x; 3.9958x over previous
//
#include <hip/hip_runtime.h>
#include <math.h>

#define SEQ   168
#define BATCH 4096
#define NOUT  9

typedef short bf16x8 __attribute__((ext_vector_type(8)));
typedef float f32x4  __attribute__((ext_vector_type(4)));

#define MFMA(a,b,c) __builtin_amdgcn_mfma_f32_16x16x32_bf16((a),(b),(c),0,0,0)

static __device__ __forceinline__ unsigned short f2bf(float f){
    unsigned int u = __builtin_bit_cast(unsigned int, f);
    return (unsigned short)((u + 0x7fffu + ((u >> 16) & 1u)) >> 16);
}
static __device__ __forceinline__ float bf2f(unsigned short h){
    unsigned int u = ((unsigned int)h) << 16;
    return __builtin_bit_cast(float, u);
}
static __device__ __forceinline__ void splitf(float f, short& hi, short& lo){
    unsigned short h = f2bf(f);
    unsigned short l2 = f2bf(f - bf2f(h));
    hi = (short)h; lo = (short)l2;
}
static __device__ __forceinline__ unsigned int packsplit(float f){
    unsigned short h = f2bf(f);
    unsigned short l2 = f2bf(f - bf2f(h));
    return (unsigned int)h | ((unsigned int)l2 << 16);
}
static __device__ __forceinline__ float sigf(float x){
    x = fminf(fmaxf(x, -30.f), 30.f);
    return __builtin_amdgcn_rcpf(1.0f + __expf(-x));
}
static __device__ __forceinline__ float tanhf_(float x){
    x = fminf(fmaxf(x, -15.f), 15.f);
    float e = __expf(2.0f * x);
    return (e - 1.0f) * __builtin_amdgcn_rcpf(e + 1.0f);
}
static __device__ __forceinline__ void unpk8(uint4 q0, uint4 q1, bf16x8& ah, bf16x8& al){
    unsigned int q[8] = {q0.x,q0.y,q0.z,q0.w,q1.x,q1.y,q1.z,q1.w};
    #pragma unroll
    for (int j=0;j<8;++j){ ah[j] = (short)(q[j] & 0xffffu); al[j] = (short)(q[j] >> 16); }
}

// ---------------- Layer 0: x[S,B,24] -> h0buf packed u32 [scnt,B,64] ----------------
__global__ __launch_bounds__(256,1)
void lstm_l0(const float* __restrict__ x,
             const float* __restrict__ Wih, const float* __restrict__ Whh,
             const float* __restrict__ bih, const float* __restrict__ bhh,
             float* __restrict__ hstate, float* __restrict__ cstate,
             unsigned int* __restrict__ h0buf, int s0, int scnt)
{
    __shared__ float        sX[2][16][28];   // x tile, stride 28 (16B-aligned, 2-way banks)
    __shared__ unsigned int hpk[2][16][68];  // packed hi|lo<<16 h_{t-1}, stride 68

    const int tid = threadIdx.x;
    const int w  = tid >> 6;       // wave id: unit group
    const int l  = tid & 63;
    const int lr = l & 15;         // A row / D col lane index
    const int g  = l >> 4;         // k-group within fragment
    const int r0 = blockIdx.x * 16;
    const int cg = w * 16 + lr;    // unit in [0,64)

    // ---- B fragments (weights), hi/lo pre-split, live in registers ----
    // ks=0: Wih0 (K=24, zero-padded to 32); ks=1,2: Whh0 (K=64)
    bf16x8 BH[4][3], BL[4][3];
    #pragma unroll
    for (int gt = 0; gt < 4; ++gt){
        const int c = gt * 64 + cg;
        bf16x8 bh = {0,0,0,0,0,0,0,0}, bl = {0,0,0,0,0,0,0,0};
        if (g < 3){
            const float* p = &Wih[c * 24 + g * 8];
            #pragma unroll
            for (int j = 0; j < 8; ++j){ short a, b_; splitf(p[j], a, b_); bh[j]=a; bl[j]=b_; }
        }
        BH[gt][0] = bh; BL[gt][0] = bl;
        #pragma unroll
        for (int ks = 0; ks < 2; ++ks){
            bf16x8 ch = {0,0,0,0,0,0,0,0}, cl = {0,0,0,0,0,0,0,0};
            const float* p = &Whh[c * 64 + ks * 32 + g * 8];
            #pragma unroll
            for (int j = 0; j < 8; ++j){ short a, b_; splitf(p[j], a, b_); ch[j]=a; cl[j]=b_; }
            BH[gt][1+ks] = ch; BL[gt][1+ks] = cl;
        }
    }
    float bias[4];
    #pragma unroll
    for (int gt = 0; gt < 4; ++gt) bias[gt] = bih[gt*64 + cg] + bhh[gt*64 + cg];

    // ---- state init: this thread owns (rows g*4+i, unit cg) ----
    float c_[4], hl_[4];
    #pragma unroll
    for (int i = 0; i < 4; ++i){
        const int R = g * 4 + i;
        float hv = 0.f, cv = 0.f;
        if (s0 != 0){
            hv = hstate[(size_t)(r0 + R) * 64 + cg];
            cv = cstate[(size_t)(r0 + R) * 64 + cg];
        }
        c_[i] = cv; hl_[i] = hv;
        hpk[0][R][cg] = packsplit(hv);
    }
    if (tid < 96){
        const float4 v = *reinterpret_cast<const float4*>(
            &x[((size_t)s0 * BATCH + r0) * 24 + tid * 4]);
        const int row = (tid * 4) / 24, col = (tid * 4) % 24;
        *reinterpret_cast<float4*>(&sX[0][row][col]) = v;
    }
    __syncthreads();

    for (int si = 0; si < scnt; ++si){
        const int p = si & 1;

        // ---- A fragments: row lr, k = ks*32 + g*8 + j (consistent with B) ----
        bf16x8 AH[3], AL[3];
        {
            bf16x8 ah = {0,0,0,0,0,0,0,0}, al = {0,0,0,0,0,0,0,0};
            if (g < 3){
                const float4 a0 = *reinterpret_cast<const float4*>(&sX[p][lr][g*8]);
                const float4 a1 = *reinterpret_cast<const float4*>(&sX[p][lr][g*8+4]);
                float v[8] = {a0.x,a0.y,a0.z,a0.w,a1.x,a1.y,a1.z,a1.w};
                #pragma unroll
                for (int j = 0; j < 8; ++j){ short a,b_; splitf(v[j],a,b_); ah[j]=a; al[j]=b_; }
            }
            AH[0] = ah; AL[0] = al;
        }
        #pragma unroll
        for (int ks = 0; ks < 2; ++ks){
            uint4 q0 = *reinterpret_cast<const uint4*>(&hpk[p][lr][ks*32 + g*8]);
            uint4 q1 = *reinterpret_cast<const uint4*>(&hpk[p][lr][ks*32 + g*8 + 4]);
            unpk8(q0, q1, AH[1+ks], AL[1+ks]);
        }

        // prefetch next x tile into registers (hidden under MFMA)
        float4 pre;
        if (tid < 96){
            const int sn = (si + 1 < scnt) ? si + 1 : si;
            pre = *reinterpret_cast<const float4*>(
                &x[((size_t)(s0 + sn) * BATCH + r0) * 24 + tid * 4]);
        }

        // ---- gates: 36 MFMAs (3 k-steps x 4 gates x 3 split terms) ----
        f32x4 acc[4];
        #pragma unroll
        for (int gt = 0; gt < 4; ++gt){ f32x4 a = {bias[gt],bias[gt],bias[gt],bias[gt]}; acc[gt] = a; }
        #pragma unroll
        for (int ks = 0; ks < 3; ++ks){
            #pragma unroll
            for (int gt = 0; gt < 4; ++gt) acc[gt] = MFMA(AH[ks], BH[gt][ks], acc[gt]);
            #pragma unroll
            for (int gt = 0; gt < 4; ++gt) acc[gt] = MFMA(AH[ks], BL[gt][ks], acc[gt]);
            #pragma unroll
            for (int gt = 0; gt < 4; ++gt) acc[gt] = MFMA(AL[ks], BH[gt][ks], acc[gt]);
        }

        // ---- nonlinearity + writes ----
        #pragma unroll
        for (int i = 0; i < 4; ++i){
            const int R = g * 4 + i;
            const float ig = sigf(acc[0][i]);
            const float fg = sigf(acc[1][i]);
            const float gg = tanhf_(acc[2][i]);
            const float og = sigf(acc[3][i]);
            c_[i] = fg * c_[i] + ig * gg;
            const float h = og * tanhf_(c_[i]);
            hl_[i] = h;
            const unsigned int pk = packsplit(h);
            hpk[p ^ 1][R][cg] = pk;
            h0buf[((size_t)si * BATCH + r0 + R) * 64 + cg] = pk;
        }
        if (tid < 96){
            const int row = (tid * 4) / 24, col = (tid * 4) % 24;
            *reinterpret_cast<float4*>(&sX[p ^ 1][row][col]) = pre;
        }
        __syncthreads();
    }

    #pragma unroll
    for (int i = 0; i < 4; ++i){
        const int R = g * 4 + i;
        cstate[(size_t)(r0 + R) * 64 + cg] = c_[i];
        hstate[(size_t)(r0 + R) * 64 + cg] = hl_[i];
    }
}

// ------------- Layer 1 + head: h0buf(packed) -> out[S,B,9] -------------
__global__ __launch_bounds__(256,1)
void lstm_l1(const unsigned int* __restrict__ h0buf,
             const float* __restrict__ Wih, const float* __restrict__ Whh,
             const float* __restrict__ bih, const float* __restrict__ bhh,
             const float* __restrict__ Wout, const float* __restrict__ bout,
             float* __restrict__ hstate, float* __restrict__ cstate,
             float* __restrict__ out, int s0, int scnt)
{
    __shared__ unsigned int sH0[2][16][68];
    __shared__ unsigned int hpk[2][16][68];

    const int tid = threadIdx.x;
    const int w  = tid >> 6;
    const int l  = tid & 63;
    const int lr = l & 15;
    const int g  = l >> 4;
    const int r0 = blockIdx.x * 16;
    const int cg = w * 16 + lr;

    // ---- weight fragments: ks 0..1 = Wih1 (h0 input), ks 2..3 = Whh1 (h1 feedback) ----
    bf16x8 BH[4][4], BL[4][4];
    #pragma unroll
    for (int gt = 0; gt < 4; ++gt){
        const int c = gt * 64 + cg;
        #pragma unroll
        for (int ks = 0; ks < 2; ++ks){
            bf16x8 bh, bl;
            const float* p = &Wih[c * 64 + ks * 32 + g * 8];
            #pragma unroll
            for (int j = 0; j < 8; ++j){ short a,b_; splitf(p[j],a,b_); bh[j]=a; bl[j]=b_; }
            BH[gt][ks] = bh; BL[gt][ks] = bl;
        }
        #pragma unroll
        for (int ks = 0; ks < 2; ++ks){
            bf16x8 bh, bl;
            const float* p = &Whh[c * 64 + ks * 32 + g * 8];
            #pragma unroll
            for (int j = 0; j < 8; ++j){ short a,b_; splitf(p[j],a,b_); bh[j]=a; bl[j]=b_; }
            BH[gt][2+ks] = bh; BL[gt][2+ks] = bl;
        }
    }
    float bias[4];
    #pragma unroll
    for (int gt = 0; gt < 4; ++gt) bias[gt] = bih[gt*64 + cg] + bhh[gt*64 + cg];

    // head weights: B col = lr (<9), k = h1 unit
    const int oc = lr;
    bf16x8 WoH[2], WoL[2];
    #pragma unroll
    for (int t = 0; t < 2; ++t){
        bf16x8 bh = {0,0,0,0,0,0,0,0}, bl = {0,0,0,0,0,0,0,0};
        if (oc < NOUT){
            const float* p = &Wout[oc * 64 + t * 32 + g * 8];
            #pragma unroll
            for (int j = 0; j < 8; ++j){ short a,b_; splitf(p[j],a,b_); bh[j]=a; bl[j]=b_; }
        }
        WoH[t] = bh; WoL[t] = bl;
    }
    const float bo0 = (oc < NOUT) ? bout[oc] : 0.f;

    float c_[4], hl_[4];
    #pragma unroll
    for (int i = 0; i < 4; ++i){
        const int R = g * 4 + i;
        float hv = 0.f, cv = 0.f;
        if (s0 != 0){
            hv = hstate[(size_t)(r0 + R) * 64 + cg];
            cv = cstate[(size_t)(r0 + R) * 64 + cg];
        }
        c_[i] = cv; hl_[i] = hv;
        hpk[0][R][cg] = packsplit(hv);
    }
    {
        const uint4 v = *reinterpret_cast<const uint4*>(
            &h0buf[((size_t)0 * BATCH + r0) * 64 + tid * 4]);
        *reinterpret_cast<uint4*>(&sH0[0][tid >> 4][(tid & 15) * 4]) = v;
    }
    __syncthreads();

    for (int si = 0; si < scnt; ++si){
        const int p = si & 1;

        // ---- A fragments ----
        bf16x8 AH[4], AL[4];
        #pragma unroll
        for (int ks = 0; ks < 2; ++ks){
            uint4 q0 = *reinterpret_cast<const uint4*>(&sH0[p][lr][ks*32 + g*8]);
            uint4 q1 = *reinterpret_cast<const uint4*>(&sH0[p][lr][ks*32 + g*8 + 4]);
            unpk8(q0, q1, AH[ks], AL[ks]);
        }
        #pragma unroll
        for (int ks = 0; ks < 2; ++ks){
            uint4 q0 = *reinterpret_cast<const uint4*>(&hpk[p][lr][ks*32 + g*8]);
            uint4 q1 = *reinterpret_cast<const uint4*>(&hpk[p][lr][ks*32 + g*8 + 4]);
            unpk8(q0, q1, AH[2+ks], AL[2+ks]);
        }

        // ---- head for step si-1 (AH[2..3] hold h1_{si-1}) on wave 0 ----
        if (w == 0 && (s0 + si) > 0){
            f32x4 ha = {bo0, bo0, bo0, bo0};
            #pragma unroll
            for (int t = 0; t < 2; ++t){
                ha = MFMA(AH[2+t], WoH[t], ha);
                ha = MFMA(AH[2+t], WoL[t], ha);
                ha = MFMA(AL[2+t], WoH[t], ha);
            }
            if (oc < NOUT){
                #pragma unroll
                for (int i = 0; i < 4; ++i)
                    out[((size_t)(s0 + si - 1) * BATCH + r0 + g*4 + i) * NOUT + oc] = ha[i];
            }
        }

        // prefetch next h0 tile
        const int sn = (si + 1 < scnt) ? si + 1 : si;
        const uint4 pre = *reinterpret_cast<const uint4*>(
            &h0buf[((size_t)sn * BATCH + r0) * 64 + tid * 4]);

        // ---- gates: 48 MFMAs ----
        f32x4 acc[4];
        #pragma unroll
        for (int gt = 0; gt < 4; ++gt){ f32x4 a = {bias[gt],bias[gt],bias[gt],bias[gt]}; acc[gt] = a; }
        #pragma unroll
        for (int ks = 0; ks < 4; ++ks){
            #pragma unroll
            for (int gt = 0; gt < 4; ++gt) acc[gt] = MFMA(AH[ks], BH[gt][ks], acc[gt]);
            #pragma unroll
            for (int gt = 0; gt < 4; ++gt) acc[gt] = MFMA(AH[ks], BL[gt][ks], acc[gt]);
            #pragma unroll
            for (int gt = 0; gt < 4; ++gt) acc[gt] = MFMA(AL[ks], BH[gt][ks], acc[gt]);
        }

        // ---- nonlinearity + writes ----
        #pragma unroll
        for (int i = 0; i < 4; ++i){
            const int R = g * 4 + i;
            const float ig = sigf(acc[0][i]);
            const float fg = sigf(acc[1][i]);
            const float gg = tanhf_(acc[2][i]);
            const float og = sigf(acc[3][i]);
            c_[i] = fg * c_[i] + ig * gg;
            const float h = og * tanhf_(c_[i]);
            hl_[i] = h;
            hpk[p ^ 1][R][cg] = packsplit(h);
        }
        *reinterpret_cast<uint4*>(&sH0[p ^ 1][tid >> 4][(tid & 15) * 4]) = pre;
        __syncthreads();
    }

    // tail head for the last step
    {
        const int p = scnt & 1;
        bf16x8 A2h[2], A2l[2];
        #pragma unroll
        for (int t = 0; t < 2; ++t){
            uint4 q0 = *reinterpret_cast<const uint4*>(&hpk[p][lr][t*32 + g*8]);
            uint4 q1 = *reinterpret_cast<const uint4*>(&hpk[p][lr][t*32 + g*8 + 4]);
            unpk8(q0, q1, A2h[t], A2l[t]);
        }
        if (w == 0){
            f32x4 ha = {bo0, bo0, bo0, bo0};
            #pragma unroll
            for (int t = 0; t < 2; ++t){
                ha = MFMA(A2h[t], WoH[t], ha);
                ha = MFMA(A2h[t], WoL[t], ha);
                ha = MFMA(A2l[t], WoH[t], ha);
            }
            if (oc < NOUT){
                #pragma unroll
                for (int i = 0; i < 4; ++i)
                    out[((size_t)(s0 + scnt - 1) * BATCH + r0 + g*4 + i) * NOUT + oc] = ha[i];
            }
        }
    }

    #pragma unroll
    for (int i = 0; i < 4; ++i){
        const int R = g * 4 + i;
        cstate[(size_t)(r0 + R) * 64 + cg] = c_[i];
        hstate[(size_t)(r0 + R) * 64 + cg] = hl_[i];
    }
}

extern "C" void kernel_launch(void* const* d_in, const int* in_sizes, int n_in,
                              void* d_out, int out_size, void* d_ws, size_t ws_size,
                              hipStream_t stream)
{
    const float* x    = (const float*)d_in[0];
    const float* Wih0 = (const float*)d_in[1];
    const float* Whh0 = (const float*)d_in[2];
    const float* bih0 = (const float*)d_in[3];
    const float* bhh0 = (const float*)d_in[4];
    const float* Wih1 = (const float*)d_in[5];
    const float* Whh1 = (const float*)d_in[6];
    const float* bih1 = (const float*)d_in[7];
    const float* bhh1 = (const float*)d_in[8];
    const float* Wout = (const float*)d_in[9];
    const float* bout = (const float*)d_in[10];
    float* out = (float*)d_out;

    float* ws = (float*)d_ws;
    const size_t BH = (size_t)BATCH * 64;     // 262144 elems
    float* h0s = ws;
    float* c0s = ws + BH;
    float* h1s = ws + 2 * BH;
    float* c1s = ws + 3 * BH;
    unsigned int* h0buf = (unsigned int*)(ws + 4 * BH);

    const size_t avail = (ws_size / 4 > 4 * BH) ? (ws_size / 4 - 4 * BH) : 0;
    int chunk = (int)(avail / BH);
    if (chunk > SEQ) chunk = SEQ;
    if (chunk < 1)  chunk = 1;

    for (int s0 = 0; s0 < SEQ; s0 += chunk){
        const int n = (SEQ - s0 < chunk) ? (SEQ - s0) : chunk;
        lstm_l0<<<BATCH/16, 256, 0, stream>>>(x, Wih0, Whh0, bih0, bhh0,
                                              h0s, c0s, h0buf, s0, n);
        lstm_l1<<<BATCH/16, 256, 0, stream>>>(h0buf, Wih1, Whh1, bih1, bhh1,
                                              Wout, bout, h1s, c1s, out, s0, n);
    }
}